// Round 3
// baseline (323.070 us; speedup 1.0000x reference)
//
#include <hip/hip_runtime.h>
#include <hip/hip_bf16.h>
#include <stdint.h>

// Problem constants (fixed by setup_inputs)
constexpr int Bn  = 8;
constexpr int Cc  = 512;
constexpr int ICc = 256;
constexpr int HWc = 48 * 48;           // 2304
constexpr float BN_EPS = 1e-5f;

typedef unsigned short u16;
typedef __attribute__((ext_vector_type(8))) short short8;   // 8 bf16 (4 VGPRs)
typedef __attribute__((ext_vector_type(4))) float f32x4;    // MFMA C/D frag

__device__ __forceinline__ u16 f2bf(float f) {
    uint32_t u = __builtin_bit_cast(uint32_t, f);
    u += 0x7fffu + ((u >> 16) & 1u);     // RNE
    return (u16)(u >> 16);
}
__device__ __forceinline__ float bf2f(u16 h) {
    uint32_t u = ((uint32_t)h) << 16;
    return __builtin_bit_cast(float, u);
}
// async global->LDS, 16B per lane; lds dst is wave-uniform base (HW adds lane*16)
__device__ __forceinline__ void load_lds16(const void* g, void* l) {
    __builtin_amdgcn_global_load_lds(
        (const __attribute__((address_space(1))) void*)(uintptr_t)g,
        (__attribute__((address_space(3))) void*)(uintptr_t)l, 16, 0, 0);
}
template <int N> __device__ __forceinline__ void wait_vmcnt() {
    if constexpr (N == 0)      asm volatile("s_waitcnt vmcnt(0)" ::: "memory");
    else if constexpr (N == 3) asm volatile("s_waitcnt vmcnt(3)" ::: "memory");
    else if constexpr (N == 4) asm volatile("s_waitcnt vmcnt(4)" ::: "memory");
    else if constexpr (N == 6) asm volatile("s_waitcnt vmcnt(6)" ::: "memory");
    else if constexpr (N == 8) asm volatile("s_waitcnt vmcnt(8)" ::: "memory");
}
__device__ __forceinline__ void wait_lgkm0() {
    asm volatile("s_waitcnt lgkmcnt(0)" ::: "memory");
}
__device__ __forceinline__ void barrier_fenced() {
    __builtin_amdgcn_s_barrier();
    asm volatile("" ::: "memory");
}

// ---------------------------------------------------------------------------
// Front cast: thph_w bf16 (rows 0..255=th_w, 256..511=ph_w), g_w bf16,
// bias_thph fp32 [th_b | ph_b].
// ---------------------------------------------------------------------------
__global__ __launch_bounds__(256)
void cast_front(const float* __restrict__ th_w, const float* __restrict__ ph_w,
                const float* __restrict__ g_w, const float* __restrict__ th_b,
                const float* __restrict__ ph_b, u16* __restrict__ wcat,
                float* __restrict__ bias_thph) {
    int idx = blockIdx.x * 256 + threadIdx.x;
    if (idx < 98304) {                           // ushort4 casts
        const float4* src;
        if (idx < 32768)       src = (const float4*)th_w + idx;
        else if (idx < 65536)  src = (const float4*)ph_w + (idx - 32768);
        else                   src = (const float4*)g_w  + (idx - 65536);
        float4 v = *src;
        ushort4 o;
        o.x = f2bf(v.x); o.y = f2bf(v.y); o.z = f2bf(v.z); o.w = f2bf(v.w);
        ((ushort4*)wcat)[idx] = o;
    } else if (idx < 98816) {                    // 512 bias floats
        int i = idx - 98304;
        bias_thph[i] = (i < 256) ? th_b[i] : ph_b[i - 256];
    }
}

__global__ __launch_bounds__(256)
void cast_w(const float* __restrict__ a, u16* __restrict__ out) {
    int idx = blockIdx.x * 256 + threadIdx.x;    // 0..32767
    float4 v = ((const float4*)a)[idx];
    ushort4 o;
    o.x = f2bf(v.x); o.y = f2bf(v.y); o.z = f2bf(v.z); o.w = f2bf(v.w);
    ((ushort4*)out)[idx] = o;
}

// ---------------------------------------------------------------------------
// x (B,C,HW) fp32 -> xt (B,HW,C) bf16, 64c x 32p LDS-tiled, ushort2 stores
// ---------------------------------------------------------------------------
__global__ __launch_bounds__(256)
void transpose_cast_x(const float* __restrict__ x, u16* __restrict__ xt) {
    __shared__ float t[64][33];
    const int b = blockIdx.z;
    const int p0 = blockIdx.x * 32;     // HW dir
    const int c0 = blockIdx.y * 64;     // C dir
    const int tx = threadIdx.x & 31, ty = threadIdx.x >> 5;   // ty 0..7
    const float* xb = x + (size_t)b * Cc * HWc;
#pragma unroll
    for (int r = 0; r < 8; ++r)
        t[r * 8 + ty][tx] = xb[(size_t)(c0 + r * 8 + ty) * HWc + p0 + tx];
    __syncthreads();
    u16* xtb = xt + (size_t)b * HWc * Cc;
    const int cc = (threadIdx.x & 31) * 2, pp = threadIdx.x >> 5;
#pragma unroll
    for (int r = 0; r < 4; ++r) {
        int p = r * 8 + pp;
        ushort2 v;
        v.x = f2bf(t[cc][p]);
        v.y = f2bf(t[cc + 1][p]);
        *(ushort2*)&xtb[(size_t)(p0 + p) * Cc + c0 + cc] = v;
    }
}

// ---------------------------------------------------------------------------
// bf16 MFMA GEMM (round-2 verified): C[m][n] = sum_k A[m][k]*B[n][k] (+bias)
// 3-buffer pipeline, counted vmcnt, LDS chunk-XOR swizzle. Used for the
// thph / g / W projections (the S/softmax/PV path is now fused_attn below).
// ---------------------------------------------------------------------------
template <int TM, int STORE, bool STATS>
__global__ __launch_bounds__(256, 2)
void mfma_gemm(const u16* __restrict__ A, const u16* __restrict__ B,
               void* __restrict__ Cout, const float* __restrict__ bias,
               int bias_mode, int K, int ldA, int ldB, int ldC,
               size_t sA, size_t sB, size_t sC,
               float* __restrict__ s0g, float* __restrict__ s1g) {
    constexpr int MI  = TM / 32;                 // 4 (TM=128) or 2 (TM=64)
    constexpr int LPS = (TM == 128) ? 4 : 3;     // global_load_lds per wave/stage
    __shared__ __align__(16) u16 As[3][TM * 32];
    __shared__ __align__(16) u16 Bs[3][128 * 32];
    const int bz = blockIdx.z;
    const int m0 = blockIdx.y * TM, n0 = blockIdx.x * 128;
    const u16* Ab = A + (size_t)bz * sA + (size_t)m0 * ldA;
    const u16* Bb = B + (size_t)bz * sB + (size_t)n0 * ldB;
    const int tid = threadIdx.x, lane = tid & 63, w = tid >> 6;
    const int wm = (w & 1) * (TM / 2);
    const int wn = (w >> 1) * 64;
    const int quad = lane >> 4, m16 = lane & 15;

    f32x4 acc[MI][4];
#pragma unroll
    for (int i = 0; i < MI; ++i)
#pragma unroll
        for (int j = 0; j < 4; ++j) acc[i][j] = (f32x4){0.f, 0.f, 0.f, 0.f};

    const int L0 = 2 * w * 64 + lane, L1 = L0 + 64;
    const int br0 = L0 >> 2, bc0 = ((L0 & 3) ^ ((L0 >> 3) & 3)) * 8;
    const int br1 = L1 >> 2, bc1 = ((L1 & 3) ^ ((L1 >> 3) & 3)) * 8;
    const int ar0 = (TM == 128) ? br0 : (tid >> 2);
    const int ac0 = (TM == 128) ? bc0 : (((tid & 3) ^ ((tid >> 3) & 3)) * 8);

    auto stage = [&](int buf, int k0) {
        if (TM == 128) {
            load_lds16(Ab + (size_t)ar0 * ldA + k0 + ac0, &As[buf][2 * w * 512]);
            load_lds16(Ab + (size_t)br1 * ldA + k0 + bc1, &As[buf][(2 * w + 1) * 512]);
        } else {
            load_lds16(Ab + (size_t)ar0 * ldA + k0 + ac0, &As[buf][w * 512]);
        }
        load_lds16(Bb + (size_t)br0 * ldB + k0 + bc0, &Bs[buf][2 * w * 512]);
        load_lds16(Bb + (size_t)br1 * ldB + k0 + bc1, &Bs[buf][(2 * w + 1) * 512]);
    };

    const int sq = (quad ^ ((m16 >> 1) & 3)) * 8;

    auto compute = [&](int buf) {
        short8 af[MI], bfv[4];
#pragma unroll
        for (int i = 0; i < MI; ++i)
            af[i] = *(const short8*)&As[buf][(wm + i * 16 + m16) * 32 + sq];
#pragma unroll
        for (int j = 0; j < 4; ++j)
            bfv[j] = *(const short8*)&Bs[buf][(wn + j * 16 + m16) * 32 + sq];
#pragma unroll
        for (int i = 0; i < MI; ++i)
#pragma unroll
            for (int j = 0; j < 4; ++j)
                acc[i][j] = __builtin_amdgcn_mfma_f32_16x16x32_bf16(
                    af[i], bfv[j], acc[i][j], 0, 0, 0);
    };

    const int nt = K / 32;
    stage(0, 0);
    stage(1, 32);

    int cur = 0;
    for (int t = 0; t < nt - 2; ++t) {
        int nxt = cur + 2; if (nxt >= 3) nxt -= 3;
        stage(nxt, (t + 2) * 32);
        wait_vmcnt<2 * LPS>();
        barrier_fenced();
        compute(cur);
        wait_lgkm0();
        barrier_fenced();
        ++cur; if (cur == 3) cur = 0;
    }
    wait_vmcnt<LPS>();
    barrier_fenced();
    compute(cur);
    wait_lgkm0();
    barrier_fenced();
    ++cur; if (cur == 3) cur = 0;
    wait_vmcnt<0>();
    barrier_fenced();
    compute(cur);

    if (bias_mode) {
#pragma unroll
        for (int i = 0; i < MI; ++i)
#pragma unroll
            for (int j = 0; j < 4; ++j)
#pragma unroll
                for (int r = 0; r < 4; ++r)
                    acc[i][j][r] += (bias_mode == 2)
                        ? bias[m0 + wm + i * 16 + quad * 4 + r]
                        : bias[n0 + wn + j * 16 + m16];
    }

    if (STORE == 0) {
        u16* C = (u16*)Cout + (size_t)bz * sC;
#pragma unroll
        for (int i = 0; i < MI; ++i) {
            int m = m0 + wm + i * 16 + quad * 4;
#pragma unroll
            for (int j = 0; j < 4; ++j) {
                int n = n0 + wn + j * 16 + m16;
#pragma unroll
                for (int r = 0; r < 4; ++r)
                    C[(size_t)(m + r) * ldC + n] = f2bf(acc[i][j][r]);
            }
        }
    } else {
        float* C = (float*)Cout + (size_t)bz * sC;
#pragma unroll
        for (int i = 0; i < MI; ++i) {
            int m = m0 + wm + i * 16 + quad * 4;
#pragma unroll
            for (int j = 0; j < 4; ++j) {
                int n = n0 + wn + j * 16 + m16;
#pragma unroll
                for (int r = 0; r < 4; ++r)
                    C[(size_t)(m + r) * ldC + n] = acc[i][j][r];
            }
        }
    }

    if (STATS) {
#pragma unroll
        for (int i = 0; i < MI; ++i) {
#pragma unroll
            for (int r = 0; r < 4; ++r) {
                float v0 = 0.f, v1 = 0.f;
#pragma unroll
                for (int j = 0; j < 4; ++j) {
                    float v = acc[i][j][r];
                    v0 += v;
                    v1 = fmaf(v, v, v1);
                }
#pragma unroll
                for (int off = 8; off; off >>= 1) {
                    v0 += __shfl_down(v0, off, 16);
                    v1 += __shfl_down(v1, off, 16);
                }
                if (m16 == 0) {
                    int m = m0 + wm + i * 16 + quad * 4 + r;
                    atomicAdd(&s0g[m], v0);
                    atomicAdd(&s1g[m], v1);
                }
            }
        }
    }
}

// ---------------------------------------------------------------------------
// Fused flash attention: S = th.ph^T (online softmax) -> y = P.g^T
//   thph: (B, HW, 512) bf16, row q = [th(256) | ph(256)]
//   g:    (B, IC=256, HW) bf16 (keys contiguous)  -> y: (B, HW, IC) bf16
// Block = (batch, 64-q tile); grid 288, bid&7=batch (pins batch's K/V to one
// XCD's L2). 4 waves.
//   QK: wave layout 2x2 (32q x 32k); Q frags held in REGISTERS (64 VGPR,
//       loaded once); K tile (64x256, 32KB) double-buffered in LDS via
//       global_load_lds with chunk-XOR swizzle (rule 21: linear dest +
//       inverse-swizzled source + swizzled read).
//   softmax: S tile bf16 in LDS (64x68 pad); each wave owns 16 rows; lane =
//       (row, 16-col slice); 2-step shfl_xor reduce; online m/l state in regs.
//   PV: wave layout 1x4 over v (all 64q x 64v); P A-frags from LDS; V B-frags
//       DIRECT global->reg (L2-resident, 1 cache line per (v,tile)); per-row
//       alpha rescale broadcast through LDS.
// LDS: 64K (Ks dbuf) + 8.7K (S) + 256B = 74.5KB -> 2 blocks/CU.
// ---------------------------------------------------------------------------
__global__ __launch_bounds__(256, 2)
void fused_attn(const u16* __restrict__ thph, const u16* __restrict__ gmat,
                u16* __restrict__ y) {
    __shared__ __align__(16) u16 Ks[2][64 * 256];   // [buf][row k][256 d] 64KB
    __shared__ __align__(16) u16 Sl[64 * 68];       // S/P tile, stride 68
    __shared__ float alpha_lds[64];                 // alpha bcast / final linv

    const int id = blockIdx.x;
    const int b = id & 7, qi = id >> 3;
    const int q0 = qi * 64;
    const u16* tB = thph + (size_t)b * HWc * 512;
    const u16* gB = gmat + (size_t)b * ICc * HWc;
    const int tid = threadIdx.x, lane = tid & 63, w = tid >> 6;
    const int quad = lane >> 4, m16 = lane & 15;
    const int wq = (w & 1) * 32, wk = (w >> 1) * 32;    // QK 2x2
    const int wv = w * 64;                               // PV v-split

    // ---- Q fragments in registers (read once): qf[i][ds]
    short8 qf[2][8];
#pragma unroll
    for (int i = 0; i < 2; ++i)
#pragma unroll
        for (int ds = 0; ds < 8; ++ds)
            qf[i][ds] = *(const short8*)&tB[(size_t)(q0 + wq + i * 16 + m16) * 512
                                            + ds * 32 + quad * 8];

    // K staging: 8 x 1KB loads per wave; slot(row r, chunk c) holds source
    // chunk c ^ (r&7)  (involution; read applies the same XOR)
    auto stageK = [&](int buf, int k0) {
#pragma unroll
        for (int u = 0; u < 8; ++u) {
            int s = (w * 8 + u) * 64 + lane;    // 16B-unit linear slot
            int r = s >> 5;                     // key row 0..63
            int c = s & 31;                     // 16B chunk 0..31
            int sc = c ^ (r & 7);
            load_lds16(tB + (size_t)(k0 + r) * 512 + 256 + sc * 8,
                       &Ks[buf][(w * 8 + u) * 512]);
        }
    };

    // softmax: this lane owns row sr (state replicated over 4 lanes)
    const int sr = w * 16 + (lane >> 2);
    const int scol = (lane & 3) * 16;
    float mrow = -3.0e38f, lrow = 0.f;

    f32x4 acc2[4][4];
#pragma unroll
    for (int i = 0; i < 4; ++i)
#pragma unroll
        for (int j = 0; j < 4; ++j) acc2[i][j] = (f32x4){0.f, 0.f, 0.f, 0.f};

    stageK(0, 0);

    for (int t = 0; t < 36; ++t) {
        const int buf = t & 1;
        if (t + 1 < 36) {
            stageK(buf ^ 1, (t + 1) * 64);
            wait_vmcnt<8>();                    // our stage(t) landed
        } else {
            wait_vmcnt<0>();
        }
        barrier_fenced();                       // A: K(t) visible; prev P consumed

        // ---- QK^T into acc1 (q=wq+i*16+quad*4+r, k=wk+j*16+m16)
        f32x4 acc1[2][2];
#pragma unroll
        for (int i = 0; i < 2; ++i)
#pragma unroll
            for (int j = 0; j < 2; ++j) acc1[i][j] = (f32x4){0.f, 0.f, 0.f, 0.f};
        const u16* kb = &Ks[buf][0];
#pragma unroll
        for (int ds = 0; ds < 8; ++ds) {
            short8 kf[2];
#pragma unroll
            for (int j = 0; j < 2; ++j) {
                int kr = wk + j * 16 + m16;
                int c  = (ds * 4 + quad) ^ (m16 & 7);   // kr&7 == m16&7
                kf[j] = *(const short8*)&kb[kr * 256 + c * 8];
            }
#pragma unroll
            for (int i = 0; i < 2; ++i)
#pragma unroll
                for (int j = 0; j < 2; ++j)
                    acc1[i][j] = __builtin_amdgcn_mfma_f32_16x16x32_bf16(
                        qf[i][ds], kf[j], acc1[i][j], 0, 0, 0);
        }

        // ---- write S tile (bf16)
#pragma unroll
        for (int i = 0; i < 2; ++i)
#pragma unroll
            for (int j = 0; j < 2; ++j)
#pragma unroll
                for (int r = 0; r < 4; ++r)
                    Sl[(wq + i * 16 + quad * 4 + r) * 68 + wk + j * 16 + m16] =
                        f2bf(acc1[i][j][r]);
        wait_lgkm0();
        barrier_fenced();                       // B: S complete

        // ---- online softmax (row sr, cols scol..scol+15)
        {
            u16* srow = &Sl[sr * 68 + scol];
            float v[16];
            short4 r0 = *(const short4*)&srow[0];
            short4 r1 = *(const short4*)&srow[4];
            short4 r2 = *(const short4*)&srow[8];
            short4 r3 = *(const short4*)&srow[12];
            v[0]=bf2f((u16)r0.x); v[1]=bf2f((u16)r0.y); v[2]=bf2f((u16)r0.z); v[3]=bf2f((u16)r0.w);
            v[4]=bf2f((u16)r1.x); v[5]=bf2f((u16)r1.y); v[6]=bf2f((u16)r1.z); v[7]=bf2f((u16)r1.w);
            v[8]=bf2f((u16)r2.x); v[9]=bf2f((u16)r2.y); v[10]=bf2f((u16)r2.z); v[11]=bf2f((u16)r2.w);
            v[12]=bf2f((u16)r3.x); v[13]=bf2f((u16)r3.y); v[14]=bf2f((u16)r3.z); v[15]=bf2f((u16)r3.w);
            float tm = v[0];
#pragma unroll
            for (int k = 1; k < 16; ++k) tm = fmaxf(tm, v[k]);
            tm = fmaxf(tm, __shfl_xor(tm, 1, 64));
            tm = fmaxf(tm, __shfl_xor(tm, 2, 64));
            float mn = fmaxf(mrow, tm);
            float a  = __expf(mrow - mn);
            float rs = 0.f;
#pragma unroll
            for (int k = 0; k < 16; ++k) { v[k] = __expf(v[k] - mn); rs += v[k]; }
            rs += __shfl_xor(rs, 1, 64);
            rs += __shfl_xor(rs, 2, 64);
            lrow = lrow * a + rs;
            mrow = mn;
            ushort4 o0 = {f2bf(v[0]), f2bf(v[1]), f2bf(v[2]), f2bf(v[3])};
            ushort4 o1 = {f2bf(v[4]), f2bf(v[5]), f2bf(v[6]), f2bf(v[7])};
            ushort4 o2 = {f2bf(v[8]), f2bf(v[9]), f2bf(v[10]), f2bf(v[11])};
            ushort4 o3 = {f2bf(v[12]), f2bf(v[13]), f2bf(v[14]), f2bf(v[15])};
            *(ushort4*)&srow[0]  = o0;
            *(ushort4*)&srow[4]  = o1;
            *(ushort4*)&srow[8]  = o2;
            *(ushort4*)&srow[12] = o3;
            if ((lane & 3) == 0) alpha_lds[sr] = a;
        }
        wait_lgkm0();
        barrier_fenced();                       // C: P + alpha ready

        // ---- PV: all 64q x v-range [wv, wv+64)
        f32x4 al[4];
#pragma unroll
        for (int i = 0; i < 4; ++i)
            al[i] = *(const f32x4*)&alpha_lds[i * 16 + quad * 4];
#pragma unroll
        for (int i = 0; i < 4; ++i)
#pragma unroll
            for (int j2 = 0; j2 < 4; ++j2)
#pragma unroll
                for (int r = 0; r < 4; ++r) acc2[i][j2][r] *= al[i][r];

        const int kbase = t * 64;
#pragma unroll
        for (int ks = 0; ks < 2; ++ks) {
            short8 pa[4];
#pragma unroll
            for (int i = 0; i < 4; ++i) {
                const u16* pr = &Sl[(i * 16 + m16) * 68 + ks * 32 + quad * 8];
                short4 lo = *(const short4*)&pr[0];
                short4 hi = *(const short4*)&pr[4];
                pa[i] = (short8){lo.x, lo.y, lo.z, lo.w, hi.x, hi.y, hi.z, hi.w};
            }
            short8 vb[4];
#pragma unroll
            for (int j2 = 0; j2 < 4; ++j2)
                vb[j2] = *(const short8*)&gB[(size_t)(wv + j2 * 16 + m16) * HWc
                                             + kbase + ks * 32 + quad * 8];
#pragma unroll
            for (int i = 0; i < 4; ++i)
#pragma unroll
                for (int j2 = 0; j2 < 4; ++j2)
                    acc2[i][j2] = __builtin_amdgcn_mfma_f32_16x16x32_bf16(
                        pa[i], vb[j2], acc2[i][j2], 0, 0, 0);
        }
        // no trailing barrier: next iteration's barrier A protects Sl rewrite
    }

    __syncthreads();
    if ((lane & 3) == 0) alpha_lds[sr] = 1.0f / lrow;   // reuse as linv
    __syncthreads();

    u16* yB = y + (size_t)b * HWc * ICc;
#pragma unroll
    for (int i = 0; i < 4; ++i) {
        f32x4 li = *(const f32x4*)&alpha_lds[i * 16 + quad * 4];
#pragma unroll
        for (int j2 = 0; j2 < 4; ++j2)
#pragma unroll
            for (int r = 0; r < 4; ++r)
                yB[(size_t)(q0 + i * 16 + quad * 4 + r) * ICc + wv + j2 * 16 + m16] =
                    f2bf(acc2[i][j2][r] * li[r]);
    }
}

// ---------------------------------------------------------------------------
// Normalize (from raw sums) + affine + residual, float4 vectorized
// ---------------------------------------------------------------------------
__global__ __launch_bounds__(256)
void bn_apply(const float* __restrict__ wy, const float* __restrict__ x,
              const float* __restrict__ s0, const float* __restrict__ s1,
              const float* __restrict__ gamma, const float* __restrict__ beta,
              float* __restrict__ out) {
    const size_t i4 = (size_t)blockIdx.x * 256 + threadIdx.x;
    const size_t base = i4 * 4;
    const int o = (int)((base / HWc) % Cc);
    const float N = (float)(Bn * HWc);
    const float mean = s0[o] / N;
    const float var  = s1[o] / N - mean * mean;
    const float rstd = rsqrtf(var + BN_EPS);
    const float ga = gamma[o];
    const float be = beta[o];
    const float4 w4 = ((const float4*)wy)[i4];
    const float4 x4 = ((const float4*)x)[i4];
    float4 r;
    r.x = (w4.x - mean) * rstd * ga + be + x4.x;
    r.y = (w4.y - mean) * rstd * ga + be + x4.y;
    r.z = (w4.z - mean) * rstd * ga + be + x4.z;
    r.w = (w4.w - mean) * rstd * ga + be + x4.w;
    ((float4*)out)[i4] = r;
}

// ---------------------------------------------------------------------------
extern "C" void kernel_launch(void* const* d_in, const int* in_sizes, int n_in,
                              void* d_out, int out_size, void* d_ws, size_t ws_size,
                              hipStream_t stream) {
    const float* x     = (const float*)d_in[0];
    const float* g_w   = (const float*)d_in[1];
    const float* g_b   = (const float*)d_in[2];
    const float* th_w  = (const float*)d_in[3];
    const float* th_b  = (const float*)d_in[4];
    const float* ph_w  = (const float*)d_in[5];
    const float* ph_b  = (const float*)d_in[6];
    const float* w_w   = (const float*)d_in[7];
    const float* w_b   = (const float*)d_in[8];
    const float* gamma = (const float*)d_in[9];
    const float* beta  = (const float*)d_in[10];

    // Workspace aliasing (113.25 MB bound):
    //  [0, 18.87M)       thph bf16 (B,HW,512)           -- live until fused done
    //  [18.87M, 28.31M)  g bf16 (B,IC,HW)               -- live until fused done
    //  [28.31M, ...)     Sreg:
    //     pre-fused:  xt bf16 (B,HW,C) [0,18.87M) + wcat + bias_thph
    //     post-fused: y bf16 (B,HW,IC) [0,9.44M); wy fp32 [9.44M,47.19M);
    //                 wbf2 [47.19M,+262K); stats [+4K)
    char* base = (char*)d_ws;
    const size_t SZT = (size_t)Bn * HWc * ICc * 2;        // 9,437,184
    u16* thph = (u16*)base;                               // 18.87 MB
    u16* g    = (u16*)(base + 2 * SZT);                   // 9.44 MB
    char* Sreg = base + 3 * SZT;
    u16* xt   = (u16*)Sreg;                               // 18.87 MB (pre-fused)
    u16* wcat = (u16*)(Sreg + (size_t)Bn * HWc * Cc * 2); // 786 KB (pre-fused)
    float* bias_thph = (float*)(Sreg + (size_t)Bn * HWc * Cc * 2 + 786432);
    u16* y    = (u16*)Sreg;                               // 9.44 MB (post-fused)
    float* wy = (float*)(Sreg + SZT);                     // 37.75 MB
    u16* wbf2 = (u16*)(Sreg + SZT + (size_t)Bn * Cc * HWc * 4);   // 262 KB
    float* stats = (float*)(Sreg + SZT + (size_t)Bn * Cc * HWc * 4 + 262144);

    dim3 blk(256);
    const u16* thphw = wcat;                   // (512,512)
    const u16* gwb   = wcat + 262144;          // (256,512)

    cast_front<<<dim3(386), blk, 0, stream>>>(th_w, ph_w, g_w, th_b, ph_b,
                                              wcat, bias_thph);
    transpose_cast_x<<<dim3(HWc / 32, Cc / 64, Bn), blk, 0, stream>>>(x, xt);

    // thph[q][o] = sum_c xt[q][c]*thph_w[o][c] + bias  (M=2304,N=512,K=512)
    mfma_gemm<128, 0, false><<<dim3(4, 18, Bn), blk, 0, stream>>>(
        xt, thphw, thph, bias_thph, 1, Cc, Cc, Cc, 512,
        (size_t)HWc * Cc, 0, (size_t)HWc * 512, nullptr, nullptr);

    // g[ic][p] = sum_c g_w[ic][c]*xt[p][c] + g_b[ic]   (M=256,N=2304,K=512)
    mfma_gemm<64, 0, false><<<dim3(18, 4, Bn), blk, 0, stream>>>(
        gwb, xt, g, g_b, 2, Cc, Cc, Cc, HWc,
        0, (size_t)HWc * Cc, (size_t)ICc * HWc, nullptr, nullptr);

    // w_w -> bf16 and zero stats (regions unused by fused)
    cast_w<<<dim3(128), blk, 0, stream>>>(w_w, wbf2);
    hipMemsetAsync(stats, 0, 2 * Cc * sizeof(float), stream);

    // fused S -> softmax -> PV  (replaces S-gemm + softmax_rows + PV-gemm)
    fused_attn<<<dim3(288), blk, 0, stream>>>(thph, g, y);

    // wy[o][p] = sum_ic w_w[o][ic]*y[p][ic] + w_b[o]  (M=512,N=2304,K=256)
    mfma_gemm<128, 1, true><<<dim3(18, 4, Bn), blk, 0, stream>>>(
        wbf2, y, wy, w_b, 2, ICc, ICc, ICc, HWc,
        0, (size_t)HWc * ICc, (size_t)Cc * HWc, stats, stats + Cc);

    // BatchNorm apply (stats from raw sums) + affine + residual
    bn_apply<<<dim3((Bn * Cc * HWc) / 4 / 256), blk, 0, stream>>>(
        wy, x, stats, stats + Cc, gamma, beta, (float*)d_out);
}